// Round 5
// baseline (342.368 us; speedup 1.0000x reference)
//
#include <hip/hip_runtime.h>
#include <stdint.h>

// Problem constants
#define B_SZ 2
#define T_SEQ 2048
#define DM 2048
#define NH 32
#define NKV 8
#define HD 64
#define QKV_W 3072

typedef unsigned short u16;
typedef __bf16 bf16x8 __attribute__((ext_vector_type(8)));
typedef float floatx4 __attribute__((ext_vector_type(4)));

__device__ __forceinline__ float bf2f(u16 u) {
  union { unsigned u; float f; } v; v.u = ((unsigned)u) << 16; return v.f;
}
__device__ __forceinline__ u16 f2bf(float f) {
  union { float f; unsigned u; } v; v.f = f;
  unsigned r = v.u + 0x7fff + ((v.u >> 16) & 1);   // RNE
  return (u16)(r >> 16);
}
// pack 2 f32 -> 2 bf16 (truncation) in one v_perm
__device__ __forceinline__ unsigned pk2bf(float hi, float lo) {
  return __builtin_amdgcn_perm(__float_as_uint(hi), __float_as_uint(lo), 0x07060302u);
}
__device__ __forceinline__ float fexp2(float x) {
#if __has_builtin(__builtin_amdgcn_exp2f)
  return __builtin_amdgcn_exp2f(x);
#else
  return exp2f(x);
#endif
}
__device__ __forceinline__ float frcp(float x) {
#if __has_builtin(__builtin_amdgcn_rcpf)
  return __builtin_amdgcn_rcpf(x);
#else
  return 1.0f / x;
#endif
}

__device__ __forceinline__ void gld_lds16(const void* g, void* l) {
  __builtin_amdgcn_global_load_lds(
      (const __attribute__((address_space(1))) unsigned int*)g,
      (__attribute__((address_space(3))) unsigned int*)l, 16, 0, 0);
}

// ---------------------------------------------------------------------------
// Fused f32 -> bf16 conversion for x, Wq, Wk, Wv (one launch).
// Segment table in float4 units: x 2097152 | Wq 1048576 | Wk 262144 | Wv 262144
// ---------------------------------------------------------------------------
__global__ __launch_bounds__(256) void conv4_kernel(
    const float* __restrict__ x, const float* __restrict__ wq,
    const float* __restrict__ wk, const float* __restrict__ wv,
    u16* __restrict__ xb, u16* __restrict__ wqkvb)
{
  const int N4 = 2097152 + 1048576 + 262144 + 262144;   // 3670016
  ushort4* xb4 = (ushort4*)xb;
  ushort4* wq4 = (ushort4*)wqkvb;                 // u16 off 0
  ushort4* wk4 = (ushort4*)(wqkvb + 2048 * 2048); // ushort4 idx base 1048576
  ushort4* wv4 = (ushort4*)(wqkvb + 2560 * 2048);
  int i = blockIdx.x * 256 + threadIdx.x;
  int stride = gridDim.x * 256;
  for (; i < N4; i += stride) {
    const float4* sp; ushort4* dp; int off;
    if (i < 2097152)      { sp = (const float4*)x;  dp = xb4; off = i; }
    else if (i < 3145728) { sp = (const float4*)wq; dp = wq4; off = i - 2097152; }
    else if (i < 3407872) { sp = (const float4*)wk; dp = wk4; off = i - 3145728; }
    else                  { sp = (const float4*)wv; dp = wv4; off = i - 3407872; }
    float4 v = sp[off];
    ushort4 o;
    o.x = f2bf(v.x); o.y = f2bf(v.y); o.z = f2bf(v.z); o.w = f2bf(v.w);
    dp[off] = o;
  }
}

// plain single-tensor conv (for Wo, after gemm_qkv frees its aliased region)
__global__ __launch_bounds__(256) void conv_kernel(
    const float* __restrict__ src, u16* __restrict__ dst, int n4)
{
  int i = blockIdx.x * 256 + threadIdx.x;
  int stride = gridDim.x * 256;
  for (; i < n4; i += stride) {
    float4 v = ((const float4*)src)[i];
    ushort4 o;
    o.x = f2bf(v.x); o.y = f2bf(v.y); o.z = f2bf(v.z); o.w = f2bf(v.w);
    ((ushort4*)dst)[i] = o;
  }
}

// ---------------------------------------------------------------------------
// GEMM1: qkv[4096,3072](bf16) = xb[4096,2048](bf16) @ wqkvb[3072,2048]^T
// ---------------------------------------------------------------------------
__global__ __launch_bounds__(256) void gemm_qkv_kernel(
    const u16* __restrict__ A, const u16* __restrict__ Bt,
    u16* __restrict__ C)
{
  __shared__ __align__(16) u16 sA[128 * 32];
  __shared__ __align__(16) u16 sB[128 * 32];

  const int n0 = blockIdx.x * 128;
  const int m0 = blockIdx.y * 128;
  const int K = 2048;

  const int tid  = threadIdx.x;
  const int lane = tid & 63;
  const int w    = tid >> 6;
  const int wm = w >> 1, wn = w & 1;
  const int lm = lane & 15, lq = lane >> 4;

  floatx4 acc[4][4];
  #pragma unroll
  for (int i = 0; i < 4; i++)
    #pragma unroll
    for (int j = 0; j < 4; j++) { floatx4 z = {0.f,0.f,0.f,0.f}; acc[i][j] = z; }

  const int ar = tid >> 2;
  const int ac = (tid & 3) * 8;
  const u16* Ap0 = A  + (size_t)(m0 + ar) * K + ac;
  const u16* Ap1 = A  + (size_t)(m0 + 64 + ar) * K + ac;
  const u16* Bp0 = Bt + (size_t)(n0 + ar) * K + ac;
  const u16* Bp1 = Bt + (size_t)(n0 + 64 + ar) * K + ac;
  u16* sAd = sA + tid * 8;
  u16* sBd = sB + tid * 8;

  for (int k0 = 0; k0 < K; k0 += 32) {
    gld_lds16(Ap0 + k0, sAd);
    gld_lds16(Ap1 + k0, sAd + 2048);
    gld_lds16(Bp0 + k0, sBd);
    gld_lds16(Bp1 + k0, sBd + 2048);
    __syncthreads();

    bf16x8 af[4], bfr[4];
    #pragma unroll
    for (int mi = 0; mi < 4; mi++)
      af[mi] = *(const bf16x8*)(sA + (wm*64 + mi*16 + lm)*32 + lq*8);
    #pragma unroll
    for (int ni = 0; ni < 4; ni++)
      bfr[ni] = *(const bf16x8*)(sB + (wn*64 + ni*16 + lm)*32 + lq*8);

    #pragma unroll
    for (int mi = 0; mi < 4; mi++)
      #pragma unroll
      for (int ni = 0; ni < 4; ni++)
        acc[mi][ni] = __builtin_amdgcn_mfma_f32_16x16x32_bf16(
            af[mi], bfr[ni], acc[mi][ni], 0, 0, 0);
    __syncthreads();
  }

  #pragma unroll
  for (int mi = 0; mi < 4; mi++)
    #pragma unroll
    for (int ni = 0; ni < 4; ni++)
      #pragma unroll
      for (int r = 0; r < 4; r++) {
        int row = m0 + wm*64 + mi*16 + lq*4 + r;
        int col = n0 + wn*64 + ni*16 + lm;
        C[(size_t)row * QKV_W + col] = f2bf(acc[mi][ni][r]);
      }
}

// ---------------------------------------------------------------------------
// GEMM2: out[4096,2048](f32) = attn[4096,2048](bf16) @ wob[2048,2048]^T(bf16)
// ---------------------------------------------------------------------------
__global__ __launch_bounds__(256) void gemm_out_kernel(
    const u16* __restrict__ A, const u16* __restrict__ Bt,
    float* __restrict__ C)
{
  __shared__ __align__(16) u16 sA[128 * 32];
  __shared__ __align__(16) u16 sB[128 * 32];

  const int n0 = blockIdx.x * 128;
  const int m0 = blockIdx.y * 128;
  const int K = 2048;

  const int tid  = threadIdx.x;
  const int lane = tid & 63;
  const int w    = tid >> 6;
  const int wm = w >> 1, wn = w & 1;
  const int lm = lane & 15, lq = lane >> 4;

  floatx4 acc[4][4];
  #pragma unroll
  for (int i = 0; i < 4; i++)
    #pragma unroll
    for (int j = 0; j < 4; j++) { floatx4 z = {0.f,0.f,0.f,0.f}; acc[i][j] = z; }

  const int ar = tid >> 2;
  const int ac = (tid & 3) * 8;
  const u16* Ap0 = A  + (size_t)(m0 + ar) * K + ac;
  const u16* Ap1 = A  + (size_t)(m0 + 64 + ar) * K + ac;
  const u16* Bp0 = Bt + (size_t)(n0 + ar) * K + ac;
  const u16* Bp1 = Bt + (size_t)(n0 + 64 + ar) * K + ac;
  u16* sAd = sA + tid * 8;
  u16* sBd = sB + tid * 8;

  for (int k0 = 0; k0 < K; k0 += 32) {
    gld_lds16(Ap0 + k0, sAd);
    gld_lds16(Ap1 + k0, sAd + 2048);
    gld_lds16(Bp0 + k0, sBd);
    gld_lds16(Bp1 + k0, sBd + 2048);
    __syncthreads();

    bf16x8 af[4], bfr[4];
    #pragma unroll
    for (int mi = 0; mi < 4; mi++)
      af[mi] = *(const bf16x8*)(sA + (wm*64 + mi*16 + lm)*32 + lq*8);
    #pragma unroll
    for (int ni = 0; ni < 4; ni++)
      bfr[ni] = *(const bf16x8*)(sB + (wn*64 + ni*16 + lm)*32 + lq*8);

    #pragma unroll
    for (int mi = 0; mi < 4; mi++)
      #pragma unroll
      for (int ni = 0; ni < 4; ni++)
        acc[mi][ni] = __builtin_amdgcn_mfma_f32_16x16x32_bf16(
            af[mi], bfr[ni], acc[mi][ni], 0, 0, 0);
    __syncthreads();
  }

  #pragma unroll
  for (int mi = 0; mi < 4; mi++)
    #pragma unroll
    for (int ni = 0; ni < 4; ni++)
      #pragma unroll
      for (int r = 0; r < 4; r++) {
        int row = m0 + wm*64 + mi*16 + lq*4 + r;
        int col = n0 + wn*64 + ni*16 + lm;
        C[(size_t)row * DM + col] = acc[mi][ni][r];
      }
}

// ---------------------------------------------------------------------------
// RoPE: q scaled by (1/sqrt(64)) * log2(e) so attention can use raw v_exp2.
// q (B,H,T,64) bf16, k (B,KV,T,64) bf16.
// ---------------------------------------------------------------------------
#define QSCALE 0.180336880f   // 0.125 * 1.44269504
__global__ __launch_bounds__(256) void rope_kernel(
    const u16* __restrict__ qkv, const float* __restrict__ cosf,
    const float* __restrict__ sinf, u16* __restrict__ qb, u16* __restrict__ kb)
{
  const int bt = blockIdx.x;
  const int b = bt / T_SEQ, t = bt % T_SEQ;
  const int tid = threadIdx.x;
  const u16* row = qkv + (size_t)bt * QKV_W;

  #pragma unroll
  for (int i = 0; i < 4; i++) {
    int idx = i * 256 + tid;          // 0..1023
    int h = idx >> 5, dp = idx & 31;
    float x1 = bf2f(row[h * 64 + dp]);
    float x2 = bf2f(row[h * 64 + dp + 32]);
    float c = cosf[t * 64 + dp];
    float s = sinf[t * 64 + dp];
    float o1 = (x1 * c - x2 * s) * QSCALE;
    float o2 = (x2 * c + x1 * s) * QSCALE;
    size_t base = ((size_t)(b * NH + h) * T_SEQ + t) * HD + dp;
    qb[base]      = f2bf(o1);
    qb[base + 32] = f2bf(o2);
  }
  {
    int idx = tid;                    // 0..255
    int kvh = idx >> 5, dp = idx & 31;
    float x1 = bf2f(row[2048 + kvh * 64 + dp]);
    float x2 = bf2f(row[2048 + kvh * 64 + dp + 32]);
    float c = cosf[t * 64 + dp];
    float s = sinf[t * 64 + dp];
    size_t base = ((size_t)(b * NKV + kvh) * T_SEQ + t) * HD + dp;
    kb[base]      = f2bf(x1 * c - x2 * s);
    kb[base + 32] = f2bf(x2 * c + x1 * s);
  }
}

// ---------------------------------------------------------------------------
// V transpose: qkv bf16 cols [2560,3072) -> vbt (B,KV,64,T) bf16
// ---------------------------------------------------------------------------
__global__ __launch_bounds__(256) void vtrans_kernel(
    const u16* __restrict__ qkv, u16* __restrict__ vbt)
{
  __shared__ u16 tile[64][66];
  const int t0  = blockIdx.x * 64;
  const int kvh = blockIdx.y;
  const int b   = blockIdx.z;
  const int tid = threadIdx.x;

  #pragma unroll
  for (int i = 0; i < 16; i++) {
    int idx = i * 256 + tid;
    int r = idx >> 6, c = idx & 63;
    tile[r][c] = qkv[(size_t)(b * T_SEQ + t0 + r) * QKV_W + 2560 + kvh * 64 + c];
  }
  __syncthreads();
  #pragma unroll
  for (int i = 0; i < 16; i++) {
    int idx = i * 256 + tid;
    int d = idx >> 6, c = idx & 63;
    vbt[((size_t)(b * NKV + kvh) * HD + d) * T_SEQ + t0 + c] = tile[c][d];
  }
}

// ---------------------------------------------------------------------------
// Flash attention v4: block = (q-tile 32, KV-GROUP, b); grid 1024; 3 blk/CU.
// Wave w = head kv*4+w; all 4 waves share double-buffered K/V LDS staging.
// One barrier per k-iteration; prefetch of tile kt+1 issued right after the
// barrier into the other buffer (latency hidden behind compute).
// S^T = K*Q^T; alpha/l transposes via __shfl (no LDS round-trip).
// ---------------------------------------------------------------------------
__global__ __launch_bounds__(256, 3) void attn_kernel(
    const u16* __restrict__ qb, const u16* __restrict__ kb,
    const u16* __restrict__ vbt, u16* __restrict__ attn)
{
  __shared__ __align__(16) u16 sK[2][64 * 64];     // 16 KB
  __shared__ __align__(16) u16 sV[2][64 * 64];     // 16 KB
  __shared__ __align__(16) u16 sP[4][2][16][72];   // 18 KB, per (wave, nq)

  const int tid  = threadIdx.x;
  const int lane = tid & 63;
  const int w    = tid >> 6;

  // block decode with long/short interleave: consecutive j alternate
  const int l   = blockIdx.x;          // 0..1023
  const int b   = l >> 9;
  const int m_  = l & 511;
  const int kv  = m_ & 7;
  const int j   = m_ >> 3;             // 0..63
  const int qt2 = (j & 1) ? (63 - (j >> 1)) : (j >> 1);
  const int h   = kv * 4 + w;
  const int nkt = (qt2 >> 1) + 1;      // number of 64-wide k tiles

  const int lm = lane & 15, lq = lane >> 4;
  const int sw = lm & 7;               // XOR chunk-swizzle key

  // Q fragments (B-operand): q = qt2*32 + nq*16 + lm, d = c*32 + lq*8
  bf16x8 qf[2][2];
  {
    const u16* qhead = qb + ((size_t)(b * NH + h) * T_SEQ + qt2 * 32) * HD;
    #pragma unroll
    for (int nq = 0; nq < 2; nq++) {
      const u16* qrow = qhead + (size_t)(nq * 16 + lm) * HD + lq * 8;
      qf[nq][0] = *(const bf16x8*)(qrow);
      qf[nq][1] = *(const bf16x8*)(qrow + 32);
    }
  }

  floatx4 o_acc[2][4];
  #pragma unroll
  for (int i = 0; i < 2; i++)
    #pragma unroll
    for (int jj = 0; jj < 4; jj++) { floatx4 z = {0.f,0.f,0.f,0.f}; o_acc[i][jj] = z; }
  float m_run[2] = {-1e30f, -1e30f};
  float l_run[2] = {0.f, 0.f};

  const u16* kbase = kb  + (size_t)(b * NKV + kv) * T_SEQ * HD;
  const u16* vbt_  = vbt + (size_t)(b * NKV + kv) * HD * T_SEQ;

  // staging lane addresses (chunk-swizzled source, contiguous LDS dest)
  const int p0row = tid >> 3,                 p1row = 32 + (tid >> 3);
  const int p0ck  = (tid & 7) ^ (p0row & 7),  p1ck  = (tid & 7) ^ (p1row & 7);
  const u16* kp0 = kbase + (size_t)p0row * HD + p0ck * 8;
  const u16* kp1 = kbase + (size_t)p1row * HD + p1ck * 8;
  const u16* vp0 = vbt_ + (size_t)p0row * T_SEQ + p0ck * 8;
  const u16* vp1 = vbt_ + (size_t)p1row * T_SEQ + p1ck * 8;
  const int d0 = tid * 16, d1 = (256 + tid) * 16;

  // stage tile 0 into buffer 0
  gld_lds16(kp0, (char*)sK[0] + d0);
  gld_lds16(kp1, (char*)sK[0] + d1);
  gld_lds16(vp0, (char*)sV[0] + d0);
  gld_lds16(vp1, (char*)sV[0] + d1);

  for (int kt = 0; kt < nkt; kt++) {
    __syncthreads();   // staging for kt complete; prior reads of other buf done
    const int cur = kt & 1;
    if (kt + 1 < nkt) {   // prefetch next tile into the other buffer
      const size_t ko = (size_t)(kt + 1) * 64 * HD;
      const int    vo = (kt + 1) * 64;
      gld_lds16(kp0 + ko, (char*)sK[1 - cur] + d0);
      gld_lds16(kp1 + ko, (char*)sK[1 - cur] + d1);
      gld_lds16(vp0 + vo, (char*)sV[1 - cur] + d0);
      gld_lds16(vp1 + vo, (char*)sV[1 - cur] + d1);
    }
    const u16* K = sK[cur];
    const u16* V = sV[cur];
    const bool last = (kt == nkt - 1);

    // K fragments (A-operand), shared across both nq
    bf16x8 kf[4][2];
    #pragma unroll
    for (int nt = 0; nt < 4; nt++) {
      kf[nt][0] = *(const bf16x8*)(K + (((nt*16 + lm) * 8 + (lq ^ sw)) << 3));
      kf[nt][1] = *(const bf16x8*)(K + (((nt*16 + lm) * 8 + ((4 + lq) ^ sw)) << 3));
    }

    // ---- phase 1: S^T + softmax + P->LDS for both nq ----
    #pragma unroll
    for (int nq = 0; nq < 2; nq++) {
      floatx4 s_acc[4];
      #pragma unroll
      for (int nt = 0; nt < 4; nt++) {
        floatx4 z = {0.f,0.f,0.f,0.f};
        z = __builtin_amdgcn_mfma_f32_16x16x32_bf16(kf[nt][0], qf[nq][0], z, 0, 0, 0);
        z = __builtin_amdgcn_mfma_f32_16x16x32_bf16(kf[nt][1], qf[nq][1], z, 0, 0, 0);
        s_acc[nt] = z;
      }

      if (last) {   // causal mask on the diagonal tile (global indices)
        #pragma unroll
        for (int nt = 0; nt < 4; nt++)
          #pragma unroll
          for (int r = 0; r < 4; r++)
            if (kt * 64 + nt * 16 + lq * 4 + r > qt2 * 32 + nq * 16 + lm)
              s_acc[nt][r] = -1e30f;
      }

      // online softmax (log2 domain); stats per q=lm
      float m01 = fmaxf(fmaxf(s_acc[0][0], s_acc[0][1]), fmaxf(s_acc[0][2], s_acc[0][3]));
      float m23 = fmaxf(fmaxf(s_acc[1][0], s_acc[1][1]), fmaxf(s_acc[1][2], s_acc[1][3]));
      float m45 = fmaxf(fmaxf(s_acc[2][0], s_acc[2][1]), fmaxf(s_acc[2][2], s_acc[2][3]));
      float m67 = fmaxf(fmaxf(s_acc[3][0], s_acc[3][1]), fmaxf(s_acc[3][2], s_acc[3][3]));
      float mloc = fmaxf(fmaxf(m01, m23), fmaxf(m45, m67));
      mloc = fmaxf(mloc, __shfl_xor(mloc, 16));
      mloc = fmaxf(mloc, __shfl_xor(mloc, 32));
      float mnew = fmaxf(m_run[nq], mloc);
      float al = fexp2(m_run[nq] - mnew);

      float rs = 0.f;
      uint2 pk[4];
      #pragma unroll
      for (int nt = 0; nt < 4; nt++) {
        float p0 = fexp2(s_acc[nt][0] - mnew);
        float p1 = fexp2(s_acc[nt][1] - mnew);
        float p2 = fexp2(s_acc[nt][2] - mnew);
        float p3 = fexp2(s_acc[nt][3] - mnew);
        rs += (p0 + p1) + (p2 + p3);
        pk[nt].x = pk2bf(p1, p0);
        pk[nt].y = pk2bf(p3, p2);
      }
      rs += __shfl_xor(rs, 16);
      rs += __shfl_xor(rs, 32);
      l_run[nq] = l_run[nq] * al + rs;
      m_run[nq] = mnew;

      // P -> LDS (A-layout: sP[w][nq][q=lm][k])
      #pragma unroll
      for (int nt = 0; nt < 4; nt++)
        *(uint2*)&sP[w][nq][lm][nt * 16 + lq * 4] = pk[nt];

      // alpha transpose via shuffle: need alpha(q = 4*lq + r)
      #pragma unroll
      for (int r = 0; r < 4; r++) {
        float ar_ = __shfl(al, 4 * lq + r);
        #pragma unroll
        for (int nd = 0; nd < 4; nd++)
          o_acc[nq][nd][r] *= ar_;
      }
    }

    // ---- phase 2: PV for both nq ----
    bf16x8 vf[4][2];
    #pragma unroll
    for (int nd = 0; nd < 4; nd++) {
      vf[nd][0] = *(const bf16x8*)(V + (((nd*16 + lm) * 8 + (lq ^ sw)) << 3));
      vf[nd][1] = *(const bf16x8*)(V + (((nd*16 + lm) * 8 + ((4 + lq) ^ sw)) << 3));
    }
    #pragma unroll
    for (int nq = 0; nq < 2; nq++)
      #pragma unroll
      for (int st = 0; st < 2; st++) {
        bf16x8 pf = *(const bf16x8*)(&sP[w][nq][lm][st * 32 + lq * 8]);
        #pragma unroll
        for (int nd = 0; nd < 4; nd++)
          o_acc[nq][nd] = __builtin_amdgcn_mfma_f32_16x16x32_bf16(
              pf, vf[nd][st], o_acc[nq][nd], 0, 0, 0);
      }
  }

  // ---- epilogue: l transpose via shuffle, normalize, store ----
  #pragma unroll
  for (int nq = 0; nq < 2; nq++) {
    #pragma unroll
    for (int r = 0; r < 4; r++) {
      float lr = __shfl(l_run[nq], 4 * lq + r);
      float ri = frcp(lr);
      size_t row = (size_t)b * T_SEQ + qt2 * 32 + nq * 16 + lq * 4 + r;
      #pragma unroll
      for (int nd = 0; nd < 4; nd++)
        attn[row * DM + h * HD + nd * 16 + lm] = f2bf(o_acc[nq][nd][r] * ri);
    }
  }
}

// ---------------------------------------------------------------------------
extern "C" void kernel_launch(void* const* d_in, const int* in_sizes, int n_in,
                              void* d_out, int out_size, void* d_ws, size_t ws_size,
                              hipStream_t stream)
{
  const float* x    = (const float*)d_in[0];
  const float* cosf = (const float*)d_in[1];
  const float* sinf = (const float*)d_in[2];
  const float* Wq   = (const float*)d_in[3];
  const float* Wk   = (const float*)d_in[4];
  const float* Wv   = (const float*)d_in[5];
  const float* Wo   = (const float*)d_in[6];
  float* out = (float*)d_out;

  char* ws = (char*)d_ws;
  u16* qkvb  = (u16*)(ws + 0);          // 4096x3072 bf16 = 25,165,824
  u16* attnb = (u16*)(ws + 0);          // reuse after rope/vtrans
  u16* qb    = (u16*)(ws + 25165824);   // 16,777,216
  u16* kb    = (u16*)(ws + 41943040);   //  4,194,304
  u16* vbt   = (u16*)(ws + 46137344);   //  4,194,304
  u16* xb    = (u16*)(ws + 50331648);   // 16,777,216 (dead after gemm_qkv)
  u16* wob   = (u16*)(ws + 50331648);   //  8,388,608 (overwrites xb)
  u16* wqkvb = (u16*)(ws + 67108864);   // 12,582,912

  dim3 blk(256);
  conv4_kernel<<<dim3(2048), blk, 0, stream>>>(x, Wq, Wk, Wv, xb, wqkvb);

  gemm_qkv_kernel<<<dim3(24, 32), blk, 0, stream>>>(xb, wqkvb, qkvb);

  conv_kernel<<<dim3(1024), blk, 0, stream>>>(Wo, wob, 4194304 / 4);

  rope_kernel<<<dim3(B_SZ * T_SEQ), blk, 0, stream>>>(qkvb, cosf, sinf, qb, kb);
  vtrans_kernel<<<dim3(T_SEQ / 64, NKV, B_SZ), blk, 0, stream>>>(qkvb, vbt);
  attn_kernel<<<dim3(1024), blk, 0, stream>>>(qb, kb, vbt, attnb);
  gemm_out_kernel<<<dim3(16, 32), blk, 0, stream>>>(attnb, wob, out);
}